// Round 1
// baseline (1198.738 us; speedup 1.0000x reference)
//
#include <hip/hip_runtime.h>

#define NNODES 100000
#define DIM 64

__global__ void deg_kernel(const int* __restrict__ src, const int* __restrict__ dst,
                           float* __restrict__ outdeg, float* __restrict__ indeg, int E) {
    int e = blockIdx.x * blockDim.x + threadIdx.x;
    if (e < E) {
        atomicAdd(&outdeg[src[e]], 1.0f);
        atomicAdd(&indeg[dst[e]], 1.0f);
    }
}

__global__ void norm_kernel(float* __restrict__ deg, int n) {
    int i = blockIdx.x * blockDim.x + threadIdx.x;
    if (i < n) {
        float d = deg[i];
        deg[i] = 1.0f / sqrtf(fmaxf(d, 1.0f));
    }
}

// 16 threads per edge; each thread handles one float4 (4 floats) of the 64-wide row.
__global__ void scatter_kernel(const float4* __restrict__ emb4,
                               const int* __restrict__ src, const int* __restrict__ dst,
                               const float* __restrict__ src_norm,
                               const float* __restrict__ dst_norm,
                               float* __restrict__ out, int E) {
    long long tid = (long long)blockIdx.x * blockDim.x + threadIdx.x;
    int e = (int)(tid >> 4);
    int q = (int)(tid & 15);
    if (e >= E) return;
    int s = src[e];
    int d = dst[e];
    float w = src_norm[s] * dst_norm[d];
    float4 v = emb4[(long long)s * 16 + q];
    float* o = out + (long long)d * DIM + q * 4;
    atomicAdd(o + 0, v.x * w);
    atomicAdd(o + 1, v.y * w);
    atomicAdd(o + 2, v.z * w);
    atomicAdd(o + 3, v.w * w);
}

extern "C" void kernel_launch(void* const* d_in, const int* in_sizes, int n_in,
                              void* d_out, int out_size, void* d_ws, size_t ws_size,
                              hipStream_t stream) {
    const float* emb = (const float*)d_in[0];
    const int* src = (const int*)d_in[1];
    const int* dst = (const int*)d_in[2];
    int E = in_sizes[1];

    float* outdeg = (float*)d_ws;          // [NNODES]
    float* indeg = outdeg + NNODES;        // [NNODES]
    float* out = (float*)d_out;

    hipMemsetAsync(outdeg, 0, 2 * NNODES * sizeof(float), stream);
    hipMemsetAsync(out, 0, (size_t)out_size * sizeof(float), stream);

    deg_kernel<<<(E + 255) / 256, 256, 0, stream>>>(src, dst, outdeg, indeg, E);
    norm_kernel<<<(2 * NNODES + 255) / 256, 256, 0, stream>>>(outdeg, 2 * NNODES);

    long long total = (long long)E * 16;
    int blocks = (int)((total + 255) / 256);
    scatter_kernel<<<blocks, 256, 0, stream>>>((const float4*)emb, src, dst,
                                               outdeg, indeg, out, E);
}

// Round 2
// 368.636 us; speedup vs baseline: 3.2518x; 3.2518x over previous
//
#include <hip/hip_runtime.h>

#define NNODES 100000
#define DIM 64

__global__ void deg_kernel(const int* __restrict__ src, const int* __restrict__ dst,
                           int* __restrict__ outdeg, int* __restrict__ indeg, int E) {
    int e = blockIdx.x * blockDim.x + threadIdx.x;
    if (e < E) {
        atomicAdd(&outdeg[src[e]], 1);
        atomicAdd(&indeg[dst[e]], 1);
    }
}

__global__ void norm_kernel(const int* __restrict__ outdeg, const int* __restrict__ indeg,
                            float* __restrict__ src_norm, float* __restrict__ dst_norm, int n) {
    int i = blockIdx.x * blockDim.x + threadIdx.x;
    if (i < n) {
        src_norm[i] = rsqrtf(fmaxf((float)outdeg[i], 1.0f));
        dst_norm[i] = rsqrtf(fmaxf((float)indeg[i], 1.0f));
    }
}

// Single-workgroup exclusive prefix scan over n ints (n ~ 100K, chunked by 1024).
__global__ void scan_kernel(const int* __restrict__ indeg, int* __restrict__ offsets, int n) {
    __shared__ int wavesums[16];
    __shared__ int carry;
    if (threadIdx.x == 0) carry = 0;
    __syncthreads();
    int lane = threadIdx.x & 63;
    int wid = threadIdx.x >> 6;
    for (int base = 0; base < n; base += 1024) {
        int i = base + threadIdx.x;
        int v = (i < n) ? indeg[i] : 0;
        // inclusive scan within wave
        int x = v;
        #pragma unroll
        for (int off = 1; off < 64; off <<= 1) {
            int y = __shfl_up(x, off, 64);
            if (lane >= off) x += y;
        }
        if (lane == 63) wavesums[wid] = x;
        __syncthreads();
        if (threadIdx.x == 0) {
            int run = 0;
            #pragma unroll
            for (int w = 0; w < 16; w++) { int t = wavesums[w]; wavesums[w] = run; run += t; }
        }
        __syncthreads();
        int excl = x - v + wavesums[wid] + carry;
        if (i < n) offsets[i] = excl;
        int incl = x + wavesums[wid] + carry;
        __syncthreads();
        if (threadIdx.x == 1023) carry = incl;
        __syncthreads();
    }
    if (threadIdx.x == 0) offsets[n] = carry;
}

__global__ void fill_kernel(const int* __restrict__ src, const int* __restrict__ dst,
                            int* __restrict__ cursor, int* __restrict__ sorted, int E) {
    int e = blockIdx.x * blockDim.x + threadIdx.x;
    if (e < E) {
        int d = dst[e];
        int pos = atomicAdd(&cursor[d], 1);
        sorted[pos] = src[e];
    }
}

// One wave per destination node; lane = feature dim (DIM == 64 == wavefront).
__global__ void aggregate_kernel(const float* __restrict__ emb,
                                 const int* __restrict__ offsets,
                                 const int* __restrict__ sorted,
                                 const float* __restrict__ src_norm,
                                 const float* __restrict__ dst_norm,
                                 float* __restrict__ out, int n) {
    int wid = threadIdx.x >> 6;
    int lane = threadIdx.x & 63;
    int node = blockIdx.x * (blockDim.x >> 6) + wid;
    if (node >= n) return;
    int beg = offsets[node];
    int end = offsets[node + 1];
    float acc = 0.0f;
    int j = beg;
    // 2-deep manual pipeline to overlap the dependent sorted[j] -> emb[row] chain
    for (; j + 2 <= end; j += 2) {
        int s0 = sorted[j];
        int s1 = sorted[j + 1];
        float w0 = src_norm[s0];
        float w1 = src_norm[s1];
        float e0 = emb[(long long)s0 * DIM + lane];
        float e1 = emb[(long long)s1 * DIM + lane];
        acc += e0 * w0;
        acc += e1 * w1;
    }
    if (j < end) {
        int s0 = sorted[j];
        acc += emb[(long long)s0 * DIM + lane] * src_norm[s0];
    }
    out[(long long)node * DIM + lane] = acc * dst_norm[node];
}

extern "C" void kernel_launch(void* const* d_in, const int* in_sizes, int n_in,
                              void* d_out, int out_size, void* d_ws, size_t ws_size,
                              hipStream_t stream) {
    const float* emb = (const float*)d_in[0];
    const int* src = (const int*)d_in[1];
    const int* dst = (const int*)d_in[2];
    int E = in_sizes[1];

    int* outdeg = (int*)d_ws;                 // [N]
    int* indeg = outdeg + NNODES;             // [N]
    int* offsets = indeg + NNODES;            // [N+1]
    int* cursor = offsets + NNODES + 1;       // [N]
    int* sorted = cursor + NNODES;            // [E]
    float* src_norm = (float*)(sorted + E);   // [N]
    float* dst_norm = src_norm + NNODES;      // [N]
    float* out = (float*)d_out;

    hipMemsetAsync(outdeg, 0, 2 * NNODES * sizeof(int), stream);

    deg_kernel<<<(E + 255) / 256, 256, 0, stream>>>(src, dst, outdeg, indeg, E);
    norm_kernel<<<(NNODES + 255) / 256, 256, 0, stream>>>(outdeg, indeg, src_norm, dst_norm, NNODES);
    scan_kernel<<<1, 1024, 0, stream>>>(indeg, offsets, NNODES);
    hipMemcpyAsync(cursor, offsets, NNODES * sizeof(int), hipMemcpyDeviceToDevice, stream);
    fill_kernel<<<(E + 255) / 256, 256, 0, stream>>>(src, dst, cursor, sorted, E);

    int waves_per_block = 4;  // 256 threads
    int blocks = (NNODES + waves_per_block - 1) / waves_per_block;
    aggregate_kernel<<<blocks, 256, 0, stream>>>(emb, offsets, sorted, src_norm, dst_norm, out, NNODES);
}

// Round 3
// 270.454 us; speedup vs baseline: 4.4323x; 1.3630x over previous
//
#include <hip/hip_runtime.h>

#define NNODES 100000
#define DIM 64
#define SCAN_BLOCKS 128
#define SCAN_THREADS 256

__global__ void deg_kernel(const int* __restrict__ src, const int* __restrict__ dst,
                           int* __restrict__ outdeg, int* __restrict__ indeg, int E) {
    int e = blockIdx.x * blockDim.x + threadIdx.x;
    if (e < E) {
        atomicAdd(&outdeg[src[e]], 1);
        atomicAdd(&indeg[dst[e]], 1);
    }
}

// scanA: per-block sums of indeg (4 ints/thread) -> partial[b]; also src_norm from outdeg.
__global__ void scanA_kernel(const int* __restrict__ indeg, const int* __restrict__ outdeg,
                             int* __restrict__ partial, float* __restrict__ src_norm, int n) {
    int tid = threadIdx.x;
    int g = blockIdx.x * blockDim.x + tid;
    int base = g * 4;
    int4 v = make_int4(0, 0, 0, 0);
    if (base < n) {
        v = *(const int4*)(indeg + base);
        int4 od = *(const int4*)(outdeg + base);
        float4 sn;
        sn.x = rsqrtf(fmaxf((float)od.x, 1.0f));
        sn.y = rsqrtf(fmaxf((float)od.y, 1.0f));
        sn.z = rsqrtf(fmaxf((float)od.z, 1.0f));
        sn.w = rsqrtf(fmaxf((float)od.w, 1.0f));
        *(float4*)(src_norm + base) = sn;
    }
    int s = v.x + v.y + v.z + v.w;
    int lane = tid & 63, wid = tid >> 6;
    #pragma unroll
    for (int off = 32; off > 0; off >>= 1) s += __shfl_down(s, off, 64);
    __shared__ int ws[4];
    if (lane == 0) ws[wid] = s;
    __syncthreads();
    if (tid == 0) partial[blockIdx.x] = ws[0] + ws[1] + ws[2] + ws[3];
}

// scanB: one block, exclusive scan of SCAN_BLOCKS partials.
__global__ void scanB_kernel(const int* __restrict__ partial, int* __restrict__ blockoff, int nb) {
    int t = threadIdx.x;
    int v = (t < nb) ? partial[t] : 0;
    int lane = t & 63, wid = t >> 6;
    int x = v;
    #pragma unroll
    for (int off = 1; off < 64; off <<= 1) {
        int y = __shfl_up(x, off, 64);
        if (lane >= off) x += y;
    }
    __shared__ int ws[2];
    if (lane == 63) ws[wid] = x;
    __syncthreads();
    int add = (wid == 1) ? ws[0] : 0;
    if (t < nb) blockoff[t] = x - v + add;
}

// scanC: full exclusive scan -> offsets AND cursor.
__global__ void scanC_kernel(const int* __restrict__ indeg, const int* __restrict__ blockoff,
                             int* __restrict__ offsets, int* __restrict__ cursor, int n, int E) {
    int tid = threadIdx.x;
    int g = blockIdx.x * blockDim.x + tid;
    int base = g * 4;
    int4 v = make_int4(0, 0, 0, 0);
    if (base < n) v = *(const int4*)(indeg + base);
    int l0 = v.x, l1 = l0 + v.y, l2 = l1 + v.z, l3 = l2 + v.w;
    int tot = l3;
    int lane = tid & 63, wid = tid >> 6;
    int x = tot;
    #pragma unroll
    for (int off = 1; off < 64; off <<= 1) {
        int y = __shfl_up(x, off, 64);
        if (lane >= off) x += y;
    }
    __shared__ int ws[4];
    if (lane == 63) ws[wid] = x;
    __syncthreads();
    int wadd = 0;
    #pragma unroll
    for (int w = 0; w < 4; w++) wadd += (w < wid) ? ws[w] : 0;
    int excl = x - tot + wadd + blockoff[blockIdx.x];
    if (base < n) {
        int4 o;
        o.x = excl; o.y = excl + l0; o.z = excl + l1; o.w = excl + l2;
        *(int4*)(offsets + base) = o;
        *(int4*)(cursor + base) = o;
    }
    if (g == 0) offsets[n] = E;
}

__global__ void fill_kernel(const int* __restrict__ src, const int* __restrict__ dst,
                            int* __restrict__ cursor, int* __restrict__ sorted, int E) {
    int e = blockIdx.x * blockDim.x + threadIdx.x;
    if (e < E) {
        int d = dst[e];
        int pos = atomicAdd(&cursor[d], 1);
        sorted[pos] = src[e];
    }
}

// One wave per destination node; lane = feature dim (DIM == 64 == wavefront).
__global__ void aggregate_kernel(const float* __restrict__ emb,
                                 const int* __restrict__ offsets,
                                 const int* __restrict__ sorted,
                                 const float* __restrict__ src_norm,
                                 float* __restrict__ out, int n) {
    int wid = threadIdx.x >> 6;
    int lane = threadIdx.x & 63;
    int node = blockIdx.x * (blockDim.x >> 6) + wid;
    if (node >= n) return;
    int beg = offsets[node];
    int end = offsets[node + 1];
    float dn = rsqrtf(fmaxf((float)(end - beg), 1.0f));
    float acc = 0.0f;
    int j = beg;
    for (; j + 2 <= end; j += 2) {
        int s0 = sorted[j];
        int s1 = sorted[j + 1];
        float w0 = src_norm[s0];
        float w1 = src_norm[s1];
        float e0 = emb[(size_t)s0 * DIM + lane];
        float e1 = emb[(size_t)s1 * DIM + lane];
        acc = fmaf(e0, w0, acc);
        acc = fmaf(e1, w1, acc);
    }
    if (j < end) {
        int s0 = sorted[j];
        acc = fmaf(emb[(size_t)s0 * DIM + lane], src_norm[s0], acc);
    }
    out[(size_t)node * DIM + lane] = acc * dn;
}

extern "C" void kernel_launch(void* const* d_in, const int* in_sizes, int n_in,
                              void* d_out, int out_size, void* d_ws, size_t ws_size,
                              hipStream_t stream) {
    const float* emb = (const float*)d_in[0];
    const int* src = (const int*)d_in[1];
    const int* dst = (const int*)d_in[2];
    int E = in_sizes[1];

    int* outdeg = (int*)d_ws;                   // [N]
    int* indeg = outdeg + NNODES;               // [N]
    int* offsets = indeg + NNODES;              // [N+4] (padded for int4 alignment)
    int* cursor = offsets + NNODES + 4;         // [N]
    int* sorted = cursor + NNODES;              // [E]
    float* src_norm = (float*)(sorted + E);     // [N]
    int* partial = (int*)(src_norm + NNODES);   // [SCAN_BLOCKS]
    int* blockoff = partial + SCAN_BLOCKS;      // [SCAN_BLOCKS]
    float* out = (float*)d_out;

    hipMemsetAsync(outdeg, 0, 2 * NNODES * sizeof(int), stream);

    deg_kernel<<<(E + 255) / 256, 256, 0, stream>>>(src, dst, outdeg, indeg, E);
    scanA_kernel<<<SCAN_BLOCKS, SCAN_THREADS, 0, stream>>>(indeg, outdeg, partial, src_norm, NNODES);
    scanB_kernel<<<1, SCAN_BLOCKS, 0, stream>>>(partial, blockoff, SCAN_BLOCKS);
    scanC_kernel<<<SCAN_BLOCKS, SCAN_THREADS, 0, stream>>>(indeg, blockoff, offsets, cursor, NNODES, E);
    fill_kernel<<<(E + 255) / 256, 256, 0, stream>>>(src, dst, cursor, sorted, E);

    int waves_per_block = 4;  // 256 threads
    int blocks = (NNODES + waves_per_block - 1) / waves_per_block;
    aggregate_kernel<<<blocks, 256, 0, stream>>>(emb, offsets, sorted, src_norm, out, NNODES);
}

// Round 4
// 255.384 us; speedup vs baseline: 4.6939x; 1.0590x over previous
//
#include <hip/hip_runtime.h>

#define NNODES 100000
#define DIM 64

// One pass over edges: push e onto dst's linked list, count out-degree of src.
__global__ void build_kernel(const int* __restrict__ src, const int* __restrict__ dst,
                             int* __restrict__ head, int* __restrict__ outdeg,
                             int* __restrict__ nxt, int E) {
    int e = blockIdx.x * blockDim.x + threadIdx.x;
    if (e < E) {
        int d = dst[e];
        int s = src[e];
        nxt[e] = atomicExch(&head[d], e);
        atomicAdd(&outdeg[s], 1);
    }
}

__global__ void norm_kernel(const int* __restrict__ outdeg, float* __restrict__ src_norm, int n) {
    int i = blockIdx.x * blockDim.x + threadIdx.x;
    if (i < n) {
        int4 v;
        int base = i * 4;
        if (base < n) {
            v = *(const int4*)(outdeg + base);
            float4 sn;
            sn.x = rsqrtf(fmaxf((float)v.x, 1.0f));
            sn.y = rsqrtf(fmaxf((float)v.y, 1.0f));
            sn.z = rsqrtf(fmaxf((float)v.z, 1.0f));
            sn.w = rsqrtf(fmaxf((float)v.w, 1.0f));
            *(float4*)(src_norm + base) = sn;
        }
    }
}

// One wave per destination node; lane = feature dim (DIM == 64 == wavefront).
// Walk the dst's edge list; list length = in-degree (dst_norm computed inline).
__global__ void aggregate_kernel(const float* __restrict__ emb,
                                 const int* __restrict__ head,
                                 const int* __restrict__ nxt,
                                 const int* __restrict__ src,
                                 const float* __restrict__ src_norm,
                                 float* __restrict__ out, int n) {
    int wid = threadIdx.x >> 6;
    int lane = threadIdx.x & 63;
    int node = blockIdx.x * (blockDim.x >> 6) + wid;
    if (node >= n) return;
    float acc = 0.0f;
    int cnt = 0;
    int e = head[node];
    while (e >= 0) {
        int s = src[e];
        int en = nxt[e];          // issue the chase early; emb/norm loads overlap it
        float w = src_norm[s];
        acc = fmaf(emb[(size_t)s * DIM + lane], w, acc);
        cnt++;
        e = en;
    }
    float dn = rsqrtf(fmaxf((float)cnt, 1.0f));
    out[(size_t)node * DIM + lane] = acc * dn;
}

extern "C" void kernel_launch(void* const* d_in, const int* in_sizes, int n_in,
                              void* d_out, int out_size, void* d_ws, size_t ws_size,
                              hipStream_t stream) {
    const float* emb = (const float*)d_in[0];
    const int* src = (const int*)d_in[1];
    const int* dst = (const int*)d_in[2];
    int E = in_sizes[1];

    int* head = (int*)d_ws;                    // [N]
    int* outdeg = head + NNODES;               // [N]
    int* nxt = outdeg + NNODES;                // [E]
    float* src_norm = (float*)(nxt + E);       // [N]
    float* out = (float*)d_out;

    hipMemsetAsync(head, 0xFF, NNODES * sizeof(int), stream);   // head = -1
    hipMemsetAsync(outdeg, 0, NNODES * sizeof(int), stream);

    build_kernel<<<(E + 255) / 256, 256, 0, stream>>>(src, dst, head, outdeg, nxt, E);
    norm_kernel<<<(NNODES / 4 + 255) / 256, 256, 0, stream>>>(outdeg, src_norm, NNODES);

    int waves_per_block = 4;  // 256 threads
    int blocks = (NNODES + waves_per_block - 1) / waves_per_block;
    aggregate_kernel<<<blocks, 256, 0, stream>>>(emb, head, nxt, src, src_norm, out, NNODES);
}